// Round 1
// baseline (120.666 us; speedup 1.0000x reference)
//
#include <hip/hip_runtime.h>
#include <math.h>

// DetectionLoss: gather-based exact reimplementation.
// pred_p3 (64,11,160,160) f32, pred_p4 (64,11,80,80), pred_p5 (64,11,40,40),
// targets_cls (64,60) i32, targets_box (64,60,4) f32.
// Loss terms are masked by pos_mask -> only B*T=3840 cells/scale matter.
// Collision tie-break: LAST target index wins the box (matches serial scatter
// lowering); class target is the union (reference sets 1.0 at every hit).

#define NCLS 6
#define NT   60
#define NB   64

__device__ __forceinline__ float iou_fn(float x1, float y1, float w1, float h1,
                                        float x2, float y2, float w2, float h2) {
    // mirror reference arithmetic exactly (compute xyxy, subtract back)
    float x11 = x1 - w1 * 0.5f, y11 = y1 - h1 * 0.5f;
    float x12 = x1 + w1 * 0.5f, y12 = y1 + h1 * 0.5f;
    float x21 = x2 - w2 * 0.5f, y21 = y2 - h2 * 0.5f;
    float x22 = x2 + w2 * 0.5f, y22 = y2 + h2 * 0.5f;
    float iw = fmaxf(fminf(x12, x22) - fmaxf(x11, x21), 0.0f);
    float ih = fmaxf(fminf(y12, y22) - fmaxf(y11, y21), 0.0f);
    float inter = iw * ih;
    float a1 = (x12 - x11) * (y12 - y11);
    float a2 = (x22 - x21) * (y22 - y21);
    return inter / (a1 + a2 - inter + 1e-7f);
}

__global__ __launch_bounds__(192)
void detloss_main(const float* __restrict__ p3, const float* __restrict__ p4,
                  const float* __restrict__ p5, const int* __restrict__ tcls,
                  const float* __restrict__ tbox, float* __restrict__ part) {
    __shared__ float sx[NT], sy[NT], sw[NT], sh[NT];
    __shared__ int   scls[NT];
    __shared__ int   skey[3][NT];
    __shared__ float bacc[12];

    const int b   = blockIdx.x;
    const int tid = threadIdx.x;

    if (tid < 12) bacc[tid] = 0.0f;
    if (tid < NT) {
        const float* tb = tbox + (size_t)(b * NT + tid) * 4;
        float x = tb[0], y = tb[1];
        sx[tid] = x; sy[tid] = y; sw[tid] = tb[2]; sh[tid] = tb[3];
        scls[tid] = tcls[b * NT + tid];
        #pragma unroll
        for (int s = 0; s < 3; ++s) {
            int W = 160 >> s;  // H == W at every scale
            int gx = (int)(x * (float)W);  // f32 mul then trunc, same as jnp
            int gy = (int)(y * (float)W);
            gx = min(max(gx, 0), W - 1);
            gy = min(max(gy, 0), W - 1);
            skey[s][tid] = (gy << 8) | gx;  // W<=160<256 -> unique encoding
        }
    }
    __syncthreads();

    if (tid < 3 * NT) {
        const int s = tid / NT;
        const int t = tid - s * NT;
        const int key = skey[s][t];
        bool winner = true;
        int mask = 0;
        for (int t2 = 0; t2 < NT; ++t2) {
            if (skey[s][t2] == key) {
                mask |= 1 << scls[t2];
                if (t2 > t) winner = false;  // last index wins the cell
            }
        }
        if (winner) {
            const int W = 160 >> s;
            const int HW = W * W;
            const float* pred = (s == 0) ? p3 : ((s == 1) ? p4 : p5);
            const int gx = key & 255, gy = key >> 8;
            const float* cell = pred + (size_t)b * 11 * HW + (size_t)gy * W + gx;

            // BCE over the 6 class channels at this cell
            float bce = 0.0f;
            #pragma unroll
            for (int c = 0; c < NCLS; ++c) {
                float xv = cell[(size_t)c * HW];
                float tv = (float)((mask >> c) & 1);
                bce += fmaxf(xv, 0.0f) - xv * tv + log1pf(expf(-fabsf(xv)));
            }
            // box channels are 7..10 (channel 6 skipped by NC+1:)
            float px = cell[(size_t)7 * HW], py = cell[(size_t)8 * HW];
            float pw = cell[(size_t)9 * HW], ph = cell[(size_t)10 * HW];
            float tx = sx[t], ty = sy[t], tw = sw[t], th = sh[t];

            float one_m_iou = 1.0f - iou_fn(px, py, pw, ph, tx, ty, tw, th);
            float one_m_inn = 1.0f - iou_fn(px, py, pw * 0.7f, ph * 0.7f,
                                            tx, ty, tw * 0.7f, th * 0.7f);

            atomicAdd(&bacc[s * 4 + 0], 1.0f);       // n_pos
            atomicAdd(&bacc[s * 4 + 1], bce);        // cls sum
            atomicAdd(&bacc[s * 4 + 2], one_m_iou);  // iou term sum
            atomicAdd(&bacc[s * 4 + 3], one_m_inn);  // inner term sum
        }
    }
    __syncthreads();
    if (tid < 12) part[b * 12 + tid] = bacc[tid];  // every slot written: poison-safe
}

__global__ __launch_bounds__(64)
void detloss_final(const float* __restrict__ part, float* __restrict__ out) {
    __shared__ float acc[12];
    const int tid = threadIdx.x;
    if (tid < 12) {
        float s = 0.0f;
        for (int bb = 0; bb < NB; ++bb) s += part[bb * 12 + tid];
        acc[tid] = s;
    }
    __syncthreads();
    if (tid == 0) {
        float cls_total = 0.0f, box_total = 0.0f;
        #pragma unroll
        for (int s = 0; s < 3; ++s) {
            float n_pos = acc[s * 4 + 0];
            float denom = n_pos + 1e-8f;
            float cls_loss   = acc[s * 4 + 1] / denom;
            float iou_term   = acc[s * 4 + 2] / denom;
            float inner_term = acc[s * 4 + 3] / denom;
            float inner_iou  = 0.5f * iou_term + 0.5f * inner_term;  // (1-INNER_W), INNER_W
            float box_loss   = 0.5f * iou_term + 0.5f * inner_iou;
            cls_total += cls_loss;
            box_total += box_loss;
        }
        cls_total *= (1.0f / 3.0f);
        box_total *= (1.0f / 3.0f);
        out[0] = 0.5f * cls_total + 7.5f * box_total;  // CLS_W, BOX_W
        out[1] = cls_total;
        out[2] = box_total;
    }
}

extern "C" void kernel_launch(void* const* d_in, const int* in_sizes, int n_in,
                              void* d_out, int out_size, void* d_ws, size_t ws_size,
                              hipStream_t stream) {
    const float* p3   = (const float*)d_in[0];
    const float* p4   = (const float*)d_in[1];
    const float* p5   = (const float*)d_in[2];
    const int*   tcls = (const int*)d_in[3];
    const float* tbox = (const float*)d_in[4];
    float* out  = (float*)d_out;
    float* part = (float*)d_ws;  // NB*12 floats = 3 KB

    detloss_main<<<NB, 192, 0, stream>>>(p3, p4, p5, tcls, tbox, part);
    detloss_final<<<1, 64, 0, stream>>>(part, out);
}